// Round 11
// baseline (574.657 us; speedup 1.0000x reference)
//
#include <hip/hip_runtime.h>
#include <math.h>

// ---------- config ----------
#define T_TOK 4096
#define DIM   2048
#define NEXP  32
#define TOPK  4
#define CAP   160          // ceil(1.25*4096/32)
#define ECAP  (NEXP*CAP)   // 5120
#define ISZ   1024         // moe intermediate
#define ISH   2048         // shared intermediate (I*NSH)

typedef short bf16x8 __attribute__((ext_vector_type(8)));
typedef float f32x4  __attribute__((ext_vector_type(4)));

__device__ __forceinline__ unsigned int f2bf(float f){
  union { float f; unsigned int u; } v; v.f = f;
  return (v.u + 0x7fffu + ((v.u >> 16) & 1u)) >> 16;   // RNE
}

// async global->LDS, 16B/lane; LDS base wave-uniform (HW adds lane*16), global addr per-lane
#define GLOAD16(g, l) __builtin_amdgcn_global_load_lds( \
    (const __attribute__((address_space(1))) unsigned int*)(g), \
    (__attribute__((address_space(3))) unsigned int*)(l), 16, 0, 0)

// ---------- fp32 -> bf16 convert (layout-preserving; shared weights) ----------
__global__ __launch_bounds__(256) void cvt_k(const float* __restrict__ in,
                                             unsigned short* __restrict__ out, int n8){
  int i = blockIdx.x*256 + threadIdx.x;
  if (i >= n8) return;
  const float4 a = *(const float4*)&in[(size_t)i*8];
  const float4 b = *(const float4*)&in[(size_t)i*8 + 4];
  uint4 v;
  v.x = f2bf(a.x) | (f2bf(a.y) << 16);
  v.y = f2bf(a.z) | (f2bf(a.w) << 16);
  v.z = f2bf(b.x) | (f2bf(b.y) << 16);
  v.w = f2bf(b.z) | (f2bf(b.w) << 16);
  *(uint4*)&out[(size_t)i*8] = v;
}

// ---------- router: fp64 logits, exact top-k semantics; also emits xbf ----------
__global__ __launch_bounds__(256) void router_k(const float* __restrict__ x,
                                                const float* __restrict__ rw,
                                                const float* __restrict__ eb,
                                                int* __restrict__ tki,
                                                float* __restrict__ tkw,
                                                unsigned short* __restrict__ xbf){
  __shared__ float  xs[4][DIM];
  __shared__ double ssh[4][NEXP];
  const int tb = blockIdx.x * 4;
  const int tid = threadIdx.x;
  for (int i = tid; i < 4*(DIM/4); i += 256){
    int t = i >> 9, c = (i & 511) << 2;
    float4 f = *(const float4*)&x[(size_t)(tb + t)*DIM + c];
    *(float4*)&xs[t][c] = f;
    uint2 w;
    w.x = f2bf(f.x) | (f2bf(f.y) << 16);
    w.y = f2bf(f.z) | (f2bf(f.w) << 16);
    *(uint2*)&xbf[(size_t)(tb + t)*DIM + c] = w;     // fused x -> bf16
  }
  __syncthreads();
  const int lane = tid & 63, wv = tid >> 6;
  for (int ei = 0; ei < 8; ++ei){
    int e = wv*8 + ei;
    double a0=0, a1=0, a2=0, a3=0;
    for (int d = lane; d < DIM; d += 64){
      double w = (double)rw[(size_t)e*DIM + d];
      a0 += (double)xs[0][d] * w;
      a1 += (double)xs[1][d] * w;
      a2 += (double)xs[2][d] * w;
      a3 += (double)xs[3][d] * w;
    }
    for (int off = 32; off; off >>= 1){
      a0 += __shfl_down(a0, off);
      a1 += __shfl_down(a1, off);
      a2 += __shfl_down(a2, off);
      a3 += __shfl_down(a3, off);
    }
    if (lane == 0){ ssh[0][e]=a0; ssh[1][e]=a1; ssh[2][e]=a2; ssh[3][e]=a3; }
  }
  __syncthreads();
  if (tid < 4){
    const int t = tid;
    double s[NEXP], sc[NEXP];
    for (int e = 0; e < NEXP; ++e){
      double sig = 1.0 / (1.0 + exp(-ssh[t][e]));
      s[e] = sig; sc[e] = sig + (double)eb[e];
    }
    double gsc[8];
    for (int g = 0; g < 8; ++g){
      double b0=sc[g*4],b1=sc[g*4+1],b2=sc[g*4+2],b3=sc[g*4+3];
      double h1=fmax(b0,b1), l1=fmin(b0,b1);
      double h2=fmax(b2,b3), l2=fmin(b2,b3);
      double top = fmax(h1,h2);
      double sec = fmax(fmin(h1,h2), (h1 >= h2) ? l1 : l2);
      gsc[g] = top + sec;
    }
    int gsel = 0;
    for (int r = 0; r < 3; ++r){
      int bi = -1; double bv = -1e300;
      for (int g = 0; g < 8; ++g)
        if (!((gsel >> g) & 1) && gsc[g] > bv){ bv = gsc[g]; bi = g; }
      gsel |= 1 << bi;
    }
    double mval[NEXP];
    for (int e = 0; e < NEXP; ++e)
      mval[e] = ((gsel >> (e >> 2)) & 1) ? sc[e] : 0.0;
    int idx4[4]; double wsum = 0.0, wv4[4];
    for (int r = 0; r < 4; ++r){
      int bi = -1; double bv = -1e300;
      for (int e = 0; e < NEXP; ++e)
        if (mval[e] > bv){ bv = mval[e]; bi = e; }
      idx4[r] = bi; mval[bi] = -1e300;
      wv4[r] = s[bi]; wsum += wv4[r];
    }
    const int gt = tb + t;
    for (int r = 0; r < 4; ++r){
      tki[gt*4 + r] = idx4[r];
      tkw[gt*4 + r] = (float)(wv4[r] / (wsum + 1e-20) * 2.5);
    }
  }
}

// ---------- dispatch: wave per expert, stable-order rank scan + tail zero-fill ----------
__global__ __launch_bounds__(1024) void dispatch_k(const int* __restrict__ tki,
                                                   const float* __restrict__ tkw,
                                                   int* __restrict__ stok,
                                                   float* __restrict__ sw){
  const int e = blockIdx.x*16 + (threadIdx.x >> 6);
  const int lane = threadIdx.x & 63;
  int base = 0;
  for (int it = 0; it < (T_TOK*TOPK)/64; ++it){
    if (base >= CAP) break;
    int idx = it*64 + lane;
    int ex = tki[idx];
    bool m = (ex == e);
    unsigned long long mk = __ballot(m);
    int pos = base + __popcll(mk & ((1ull << lane) - 1ull));
    if (m && pos < CAP){
      stok[e*CAP + pos] = idx >> 2;
      sw[e*CAP + pos]   = tkw[idx];
    }
    base += __popcll(mk);
  }
  const int count = (base < CAP) ? base : CAP;
  for (int s2 = count + lane; s2 < CAP; s2 += 64){
    stok[e*CAP + s2] = 0;
    sw[e*CAP + s2]   = 0.f;
  }
}

// ---------- GEMM body: 8-wave MFMA, 3-deep counted-vmcnt pipeline ----------
// MODE 0 EGU: hex(bf16)=silu(X@Wg)*(X@Wu); A gathered; B fp32 [K,1024]; 64g+64u; 512 blocks.
// MODE 1 EDN: out += atomic scatter(sw*(hex@Wd)); B fp32 [K,2048]; 128 cols; 512 blocks.
// MODE 2 SGU: hsh(bf16)=silu(X@sg^T)*(X@su^T); both bf16 gload; BM=256, 64g+64u; 512 blocks.
// MODE 3 SDN: out += atomic (hsh@sd^T); both bf16 gload; BM=256, 64 cols; 512 blocks (out pre-zeroed).
template<int MODE>
__device__ __forceinline__ void gemm_body(int idx, uint4* ldsroot,
    const unsigned short* __restrict__ Ab,
    const void* __restrict__ B0v, const void* __restrict__ B1v,
    void* __restrict__ Co,
    const int* __restrict__ stok, const float* __restrict__ sw)
{
  constexpr int BM   = (MODE < 2) ? 160 : 256;
  constexpr int APL  = BM/16;                       // 10,10,16,16
  constexpr int FM   = (MODE < 2) ? 5 : 4;          // m-frags per wave
  constexpr int KK   = (MODE == 1) ? ISZ : DIM;
  constexpr int BPL  = (MODE == 3) ? 4 : 8;         // B planes
  constexpr int NBF  = (MODE == 2) ? 4 : 2;         // B frags per wave
  constexpr int TPL  = APL + BPL;                   // 18,18,24,20
  constexpr int NT   = KK/32;
  constexpr int LDB  = (MODE == 0) ? ISZ : DIM;     // fp32 B n-stride
  constexpr int LDC  = (MODE == 0) ? ISZ : ((MODE == 2) ? ISH : DIM);
  constexpr int SAIT = (MODE >= 2) ? 3 : 2;

  const int tid  = threadIdx.x;
  const int lane = tid & 63, wid = tid >> 6;

  int e = 0, mb = 0, nb = 0;
  if constexpr (MODE < 2){
    // XCD-aware: idx%8 -> experts 4x..4x+3 grouped (A-tile L2 reuse); 16 nblks
    const int x = idx & 7, s = idx >> 3;
    e  = x*4 + (s & 3);
    nb = (s >> 2) * (MODE == 0 ? 64 : 128);
  } else {
    mb = (idx & 15)*256; nb = (idx >> 4)*64;        // 32 nblks, same-n adjacent
  }

  // ---- gload plane pointers (A always; B too for MODE>=2) ----
  const unsigned short* gptr[SAIT];
  #pragma unroll
  for (int i = 0; i < SAIT; ++i){
    int p = wid + i*8;
    int pp = (p < ((MODE >= 2) ? TPL : APL)) ? p : 0;
    if (pp < APL){
      int r = pp*16 + (lane & 15);
      int row;
      if constexpr (MODE == 0)      row = stok[e*CAP + r];
      else if constexpr (MODE == 1) row = e*CAP + r;
      else                          row = mb + r;
      gptr[i] = Ab + (size_t)row*KK + (lane >> 4)*8;
    } else {
      int q = pp - APL;
      const unsigned short* src = (const unsigned short*)B0v;
      int n;
      if constexpr (MODE == 2){ if (q & 1) src = (const unsigned short*)B1v;
                                n = nb + (q >> 1)*16 + (lane & 15); }
      else                    { n = nb + q*16 + (lane & 15); }
      gptr[i] = src + (size_t)n*KK + (lane >> 4)*8;
    }
  }
  auto stageG = [&](int k0, int buf){
    char* base = (char*)ldsroot + (size_t)buf*TPL*1024;
    #pragma unroll
    for (int i = 0; i < SAIT; ++i){
      int p = wid + i*8;
      if (p < ((MODE >= 2) ? TPL : APL))
        GLOAD16(gptr[i] + k0, base + p*1024);
    }
  };

  // ---- fp32 B reg-staging (MODE<=1): thread = (plane, col, k-oct) ----
  const int bq   = (tid & 127) >> 4;    // plane 0..7
  const int bcl  = tid & 15;            // col within plane
  const int boct = tid >> 7;            // k-oct 0..3
  const float* bkn = nullptr;
  if constexpr (MODE == 0){
    const float* src = (const float*)((bq & 1) ? B1v : B0v);
    int n0 = nb + (bq >> 1)*16 + bcl;
    bkn = src + (size_t)e*KK*LDB + (size_t)boct*8*LDB + n0;
  } else if constexpr (MODE == 1){
    bkn = (const float*)B0v + (size_t)e*KK*LDB + (size_t)boct*8*LDB + (nb + bq*16 + bcl);
  }
  auto loadB = [&](int k0, float (&br)[8]){
    const float* p = bkn + (size_t)k0*LDB;
    #pragma unroll
    for (int j = 0; j < 8; ++j) br[j] = p[(size_t)j*LDB];
  };
  auto writeB = [&](int buf, const float (&br)[8]){
    uint4 v;
    v.x = f2bf(br[0]) | (f2bf(br[1]) << 16);
    v.y = f2bf(br[2]) | (f2bf(br[3]) << 16);
    v.z = f2bf(br[4]) | (f2bf(br[5]) << 16);
    v.w = f2bf(br[6]) | (f2bf(br[7]) << 16);
    *(uint4*)((char*)ldsroot + (size_t)buf*TPL*1024 + (APL + bq)*1024 + boct*256 + bcl*16) = v;
  };

  // counted waits: K = own loads issued per step (per-wave)
  auto waitK = [&]{
    if constexpr (MODE <= 1){
      if (wid < 2) asm volatile("s_waitcnt vmcnt(10)" ::: "memory");
      else         asm volatile("s_waitcnt vmcnt(9)"  ::: "memory");
      asm volatile("s_waitcnt lgkmcnt(0)" ::: "memory");
    } else if constexpr (MODE == 2){
      asm volatile("s_waitcnt vmcnt(3)" ::: "memory");
    } else {
      if (wid < 4) asm volatile("s_waitcnt vmcnt(3)" ::: "memory");
      else         asm volatile("s_waitcnt vmcnt(2)" ::: "memory");
    }
  };

  // ---- compute-side wave assignment: MODE<2 2m x 4n; MODE>=2 4m x 2n ----
  const int wmp = (MODE < 2) ? (wid >> 2)*FM : (wid >> 1)*FM;
  const int wq  = (MODE < 2) ? (wid & 3) : (wid & 1);
  f32x4 acc[FM][NBF];
  #pragma unroll
  for (int i = 0; i < FM; ++i)
    #pragma unroll
    for (int j = 0; j < NBF; ++j) acc[i][j] = f32x4{0,0,0,0};

  float brA[8], brB[8];

  // ---- prologue: two stages in flight ----
  stageG(0, 0);
  if constexpr (MODE <= 1) loadB(0, brA);
  stageG(32, 1);
  if constexpr (MODE <= 1){ loadB(32, brB); writeB(0, brA); }
  waitK();
  __builtin_amdgcn_s_barrier();

  int cons = 0;
  auto step = [&](int t, float (&brW)[8], float (&brL)[8]){
    const int stg = (cons >= 1) ? cons - 1 : 2;         // (cons+2)%3
    const int nxt = (cons == 2) ? 0 : cons + 1;
    if (t + 2 < NT){
      stageG((t+2)*32, stg);
      if constexpr (MODE <= 1) loadB((t+2)*32, brL);
    }
    __builtin_amdgcn_sched_barrier(0);                  // pin issues early
    const char* L = (const char*)ldsroot + (size_t)cons*TPL*1024;
    bf16x8 af[FM], bfr[NBF];
    #pragma unroll
    for (int i = 0; i < FM; ++i)
      af[i] = *(const bf16x8*)(L + (wmp + i)*1024 + lane*16);
    #pragma unroll
    for (int j = 0; j < NBF; ++j)
      bfr[j] = *(const bf16x8*)(L + (APL + wq*NBF + j)*1024 + lane*16);
    #pragma unroll
    for (int i = 0; i < FM; ++i)
      #pragma unroll
      for (int j = 0; j < NBF; ++j)
        acc[i][j] = __builtin_amdgcn_mfma_f32_16x16x32_bf16(af[i], bfr[j], acc[i][j], 0, 0, 0);
    if constexpr (MODE <= 1){
      if (t + 1 < NT) writeB(nxt, brW);
    }
    if (t + 2 < NT){
      waitK();                                          // leave t+2 batch in flight
    } else if (t == NT - 2){
      asm volatile("s_waitcnt vmcnt(0)" ::: "memory");
      if constexpr (MODE <= 1) asm volatile("s_waitcnt lgkmcnt(0)" ::: "memory");
    }
    if (t < NT - 1) __builtin_amdgcn_s_barrier();
    cons = nxt;
  };

  for (int t2 = 0; t2 < NT/2; ++t2){
    step(2*t2,     brB, brA);
    step(2*t2 + 1, brA, brB);
  }

  // ---- epilogue ----
  const int cl = lane & 15, rg = (lane >> 4)*4;
  #pragma unroll
  for (int i = 0; i < FM; ++i){
    #pragma unroll
    for (int r = 0; r < 4; ++r){
      const int m = wmp*16 + i*16 + rg + r;
      if constexpr (MODE == 0){
        float g = acc[i][0][r], u = acc[i][1][r];
        float h = g / (1.f + __expf(-g)) * u;
        int gcol = nb + wq*16 + cl;
        ((unsigned short*)Co)[(size_t)(e*CAP + m)*LDC + gcol] = (unsigned short)f2bf(h);
      } else if constexpr (MODE == 2){
        #pragma unroll
        for (int jj = 0; jj < 2; ++jj){
          float g = acc[i][jj*2][r], u = acc[i][jj*2+1][r];
          float h = g / (1.f + __expf(-g)) * u;
          int gcol = nb + wq*32 + jj*16 + cl;
          ((unsigned short*)Co)[(size_t)(mb + m)*LDC + gcol] = (unsigned short)f2bf(h);
        }
      } else if constexpr (MODE == 1){
        const int slot = e*CAP + m;
        float w = sw[slot];
        if (w != 0.f){
          int tok = stok[slot];
          #pragma unroll
          for (int j = 0; j < 2; ++j){
            int c = nb + wq*32 + j*16 + cl;
            atomicAdd(&((float*)Co)[(size_t)tok*DIM + c], w * acc[i][j][r]);
          }
        }
      } else {
        #pragma unroll
        for (int j = 0; j < 2; ++j){
          int c = nb + wq*32 + j*16 + cl;
          atomicAdd(&((float*)Co)[(size_t)(mb + m)*DIM + c], acc[i][j][r]);
        }
      }
    }
  }
}

// ---------- F1: EGU(512) || SGU(512) + 64 out-zero blocks ----------
__global__ __launch_bounds__(512, 2)
void fusedGU_k(const unsigned short* __restrict__ xbf,
               const float* __restrict__ wg, const float* __restrict__ wu,
               const unsigned short* __restrict__ sgb, const unsigned short* __restrict__ sub_,
               unsigned short* __restrict__ hex, unsigned short* __restrict__ hsh,
               float* __restrict__ out,
               const int* __restrict__ stok, const float* __restrict__ sw){
  __shared__ uint4 lds[3*24*64];                      // 72 KB (max TPL=24)
  const int bid = blockIdx.x;
  if (bid >= 1024){                                   // zero `out` for F2 atomics
    float4 z{0.f,0.f,0.f,0.f};
    for (int i = (bid - 1024)*512 + (int)threadIdx.x; i < T_TOK*DIM/4; i += 64*512)
      ((float4*)out)[i] = z;
    return;
  }
  const int sb = bid & 255, round = bid >> 8;
  const int idx = (round >> 1)*256 + sb;              // per-CU mix: rounds alternate modes
  if (round & 1) gemm_body<2>(idx, lds, xbf, sgb, sub_, hsh, nullptr, nullptr);
  else           gemm_body<0>(idx, lds, xbf, wg, wu, hex, stok, sw);
}

// ---------- F2: EDN(512) || SDN(512), both atomic into pre-zeroed out ----------
__global__ __launch_bounds__(512, 2)
void fusedDN_k(const unsigned short* __restrict__ hex,
               const unsigned short* __restrict__ hsh,
               const float* __restrict__ wd, const unsigned short* __restrict__ sdb,
               float* __restrict__ out,
               const int* __restrict__ stok, const float* __restrict__ sw){
  __shared__ uint4 lds[3*20*64];                      // 60 KB (max TPL=20)
  const int bid = blockIdx.x;
  const int sb = bid & 255, round = bid >> 8;
  const int idx = (round >> 1)*256 + sb;
  if (round & 1) gemm_body<3>(idx, lds, hsh, sdb, nullptr, out, nullptr, nullptr);
  else           gemm_body<1>(idx, lds, hex, wd, nullptr, out, stok, sw);
}

extern "C" void kernel_launch(void* const* d_in, const int* in_sizes, int n_in,
                              void* d_out, int out_size, void* d_ws, size_t ws_size,
                              hipStream_t stream){
  const float* x  = (const float*)d_in[0];
  const float* rw = (const float*)d_in[1];
  const float* eb = (const float*)d_in[2];
  const float* wg = (const float*)d_in[3];
  const float* wu = (const float*)d_in[4];
  const float* wd = (const float*)d_in[5];
  const float* sg = (const float*)d_in[6];
  const float* su = (const float*)d_in[7];
  const float* sd = (const float*)d_in[8];
  float* out = (float*)d_out;

  char* ws = (char*)d_ws;
  unsigned short* xbf = (unsigned short*)ws; ws += (size_t)T_TOK*DIM*2;
  unsigned short* hsh = (unsigned short*)ws; ws += (size_t)T_TOK*ISH*2;
  unsigned short* hex = (unsigned short*)ws; ws += (size_t)ECAP*ISZ*2;
  unsigned short* sgb = (unsigned short*)ws; ws += (size_t)ISH*DIM*2;
  unsigned short* sub = (unsigned short*)ws; ws += (size_t)ISH*DIM*2;
  unsigned short* sdb = (unsigned short*)ws; ws += (size_t)DIM*ISH*2;
  int*   tki  = (int*)ws;   ws += (size_t)T_TOK*TOPK*4;
  float* tkw  = (float*)ws; ws += (size_t)T_TOK*TOPK*4;
  int*   stok = (int*)ws;   ws += (size_t)ECAP*4;
  float* sw   = (float*)ws; ws += (size_t)ECAP*4;

  // router (also emits xbf); shared weights -> bf16; dispatch (self-zeroing)
  router_k<<<T_TOK/4, 256, 0, stream>>>(x, rw, eb, tki, tkw, xbf);
  cvt_k<<<((size_t)ISH*DIM/8)/256, 256, 0, stream>>>(sg, sgb, ISH*DIM/8);
  cvt_k<<<((size_t)ISH*DIM/8)/256, 256, 0, stream>>>(su, sub, ISH*DIM/8);
  cvt_k<<<((size_t)DIM*ISH/8)/256, 256, 0, stream>>>(sd, sdb, DIM*ISH/8);
  dispatch_k<<<2, 1024, 0, stream>>>(tki, tkw, stok, sw);

  // F1: expert gate/up || shared gate/up (+ zero out); F2: both down paths atomically
  fusedGU_k<<<1088, 512, 0, stream>>>(xbf, wg, wu, sgb, sub, hex, hsh, out, stok, sw);
  fusedDN_k<<<1024, 512, 0, stream>>>(hex, hsh, wd, sdb, out, stok, sw);
}

// Round 12
// 519.656 us; speedup vs baseline: 1.1058x; 1.1058x over previous
//
#include <hip/hip_runtime.h>
#include <math.h>

// ---------- config ----------
#define T_TOK 4096
#define DIM   2048
#define NEXP  32
#define TOPK  4
#define CAP   160          // ceil(1.25*4096/32)
#define ECAP  (NEXP*CAP)   // 5120
#define ISZ   1024         // moe intermediate
#define ISH   2048         // shared intermediate (I*NSH)

typedef short bf16x8 __attribute__((ext_vector_type(8)));
typedef float f32x4  __attribute__((ext_vector_type(4)));

__device__ __forceinline__ unsigned int f2bf(float f){
  union { float f; unsigned int u; } v; v.f = f;
  return (v.u + 0x7fffu + ((v.u >> 16) & 1u)) >> 16;   // RNE
}

// async global->LDS, 16B/lane; LDS base wave-uniform (HW adds lane*16), global addr per-lane
#define GLOAD16(g, l) __builtin_amdgcn_global_load_lds( \
    (const __attribute__((address_space(1))) unsigned int*)(g), \
    (__attribute__((address_space(3))) unsigned int*)(l), 16, 0, 0)

// ---------- router: fp64 logits, exact top-k; emits xbf; converts shared weights ----------
__global__ __launch_bounds__(256) void router_k(const float* __restrict__ x,
                                                const float* __restrict__ rw,
                                                const float* __restrict__ eb,
                                                int* __restrict__ tki,
                                                float* __restrict__ tkw,
                                                unsigned short* __restrict__ xbf,
                                                const float* __restrict__ sg,
                                                const float* __restrict__ su,
                                                const float* __restrict__ sd,
                                                unsigned short* __restrict__ sgb,
                                                unsigned short* __restrict__ sub_,
                                                unsigned short* __restrict__ sdb){
  __shared__ float  xs[4][DIM];
  __shared__ double ssh[4][NEXP];
  const int tb = blockIdx.x * 4;
  const int tid = threadIdx.x;
  for (int i = tid; i < 4*(DIM/4); i += 256){
    int t = i >> 9, c = (i & 511) << 2;
    float4 f = *(const float4*)&x[(size_t)(tb + t)*DIM + c];
    *(float4*)&xs[t][c] = f;
    uint2 w;
    w.x = f2bf(f.x) | (f2bf(f.y) << 16);
    w.y = f2bf(f.z) | (f2bf(f.w) << 16);
    *(uint2*)&xbf[(size_t)(tb + t)*DIM + c] = w;     // fused x -> bf16
  }
  __syncthreads();
  const int lane = tid & 63, wv = tid >> 6;
  for (int ei = 0; ei < 8; ++ei){
    int e = wv*8 + ei;
    double a0=0, a1=0, a2=0, a3=0;
    for (int d = lane; d < DIM; d += 64){
      double w = (double)rw[(size_t)e*DIM + d];
      a0 += (double)xs[0][d] * w;
      a1 += (double)xs[1][d] * w;
      a2 += (double)xs[2][d] * w;
      a3 += (double)xs[3][d] * w;
    }
    for (int off = 32; off; off >>= 1){
      a0 += __shfl_down(a0, off);
      a1 += __shfl_down(a1, off);
      a2 += __shfl_down(a2, off);
      a3 += __shfl_down(a3, off);
    }
    if (lane == 0){ ssh[0][e]=a0; ssh[1][e]=a1; ssh[2][e]=a2; ssh[3][e]=a3; }
  }
  __syncthreads();
  if (tid < 4){
    const int t = tid;
    double s[NEXP], sc[NEXP];
    for (int e = 0; e < NEXP; ++e){
      double sig = 1.0 / (1.0 + exp(-ssh[t][e]));
      s[e] = sig; sc[e] = sig + (double)eb[e];
    }
    double gsc[8];
    for (int g = 0; g < 8; ++g){
      double b0=sc[g*4],b1=sc[g*4+1],b2=sc[g*4+2],b3=sc[g*4+3];
      double h1=fmax(b0,b1), l1=fmin(b0,b1);
      double h2=fmax(b2,b3), l2=fmin(b2,b3);
      double top = fmax(h1,h2);
      double sec = fmax(fmin(h1,h2), (h1 >= h2) ? l1 : l2);
      gsc[g] = top + sec;
    }
    int gsel = 0;
    for (int r = 0; r < 3; ++r){
      int bi = -1; double bv = -1e300;
      for (int g = 0; g < 8; ++g)
        if (!((gsel >> g) & 1) && gsc[g] > bv){ bv = gsc[g]; bi = g; }
      gsel |= 1 << bi;
    }
    double mval[NEXP];
    for (int e = 0; e < NEXP; ++e)
      mval[e] = ((gsel >> (e >> 2)) & 1) ? sc[e] : 0.0;
    int idx4[4]; double wsum = 0.0, wv4[4];
    for (int r = 0; r < 4; ++r){
      int bi = -1; double bv = -1e300;
      for (int e = 0; e < NEXP; ++e)
        if (mval[e] > bv){ bv = mval[e]; bi = e; }
      idx4[r] = bi; mval[bi] = -1e300;
      wv4[r] = s[bi]; wsum += wv4[r];
    }
    const int gt = tb + t;
    for (int r = 0; r < 4; ++r){
      tki[gt*4 + r] = idx4[r];
      tkw[gt*4 + r] = (float)(wv4[r] / (wsum + 1e-20) * 2.5);
    }
  }
  // ---- fused shared-weight fp32->bf16 (waves 1-3 overlap the serial top-k tail) ----
  // 3 x 2^19 chunks of 8 elems; 1024 blocks x 1536 chunks each (exact cover)
  #pragma unroll
  for (int i = 0; i < 6; ++i){
    int g = blockIdx.x*1536 + i*256 + tid;
    const float* src; unsigned short* dst;
    int local = g & 524287;
    int sel = g >> 19;
    src = (sel == 0) ? sg : (sel == 1) ? su : sd;
    dst = (sel == 0) ? sgb : (sel == 1) ? sub_ : sdb;
    const float4 a = *(const float4*)&src[(size_t)local*8];
    const float4 b = *(const float4*)&src[(size_t)local*8 + 4];
    uint4 v;
    v.x = f2bf(a.x) | (f2bf(a.y) << 16);
    v.y = f2bf(a.z) | (f2bf(a.w) << 16);
    v.z = f2bf(b.x) | (f2bf(b.y) << 16);
    v.w = f2bf(b.z) | (f2bf(b.w) << 16);
    *(uint4*)&dst[(size_t)local*8] = v;
  }
}

// ---------- dispatch: wave per expert, stable-order rank scan + tail zero-fill ----------
__global__ __launch_bounds__(1024) void dispatch_k(const int* __restrict__ tki,
                                                   const float* __restrict__ tkw,
                                                   int* __restrict__ stok,
                                                   float* __restrict__ sw){
  const int e = blockIdx.x*16 + (threadIdx.x >> 6);
  const int lane = threadIdx.x & 63;
  int base = 0;
  for (int it = 0; it < (T_TOK*TOPK)/64; ++it){
    if (base >= CAP) break;
    int idx = it*64 + lane;
    int ex = tki[idx];
    bool m = (ex == e);
    unsigned long long mk = __ballot(m);
    int pos = base + __popcll(mk & ((1ull << lane) - 1ull));
    if (m && pos < CAP){
      stok[e*CAP + pos] = idx >> 2;
      sw[e*CAP + pos]   = tkw[idx];
    }
    base += __popcll(mk);
  }
  const int count = (base < CAP) ? base : CAP;
  for (int s2 = count + lane; s2 < CAP; s2 += 64){
    stok[e*CAP + s2] = 0;
    sw[e*CAP + s2]   = 0.f;
  }
}

// ---------- fat-tile 8-wave MFMA GEMM, 3-deep counted-vmcnt pipeline (R10) ----------
// MODE 0 EGU: hex(bf16)=silu(X@Wg)*(X@Wu); A gathered; B fp32 [K,1024]; BN=64+64; grid 512 (2/CU).
// MODE 1 EDN: out += scatter(sw*(hex@Wd)); B fp32 [K,2048]; BN=128; grid 512 (2/CU).
// MODE 2 SGU: hsh=silu(X@sg^T)*(X@su^T); both bf16 gload; BM=256, BN=128+128; grid 256.
// MODE 3 SDN: out(f32 plain)=hsh@sd^T; both bf16 gload; BM=256, BN=128; grid 256.
template<int MODE>
__global__ __launch_bounds__(512, 2)
void gemm9_k(const unsigned short* __restrict__ Ab,
             const void* __restrict__ B0v, const void* __restrict__ B1v,
             void* __restrict__ Co,
             const int* __restrict__ stok, const float* __restrict__ sw){
  constexpr int BM   = (MODE < 2) ? 160 : 256;
  constexpr int APL  = BM/16;                       // 10,10,16,16
  constexpr int FM   = BM/32;                       // 5,5,8,8
  constexpr int KK   = (MODE == 1) ? ISZ : DIM;
  constexpr int BPL  = (MODE == 2) ? 16 : 8;        // B planes
  constexpr int NBF  = BPL/4;                       // B frags per wave (2,2,4,2)
  constexpr int TPL  = APL + BPL;                   // 18,18,32,24
  constexpr int NT   = KK/32;
  constexpr int LDB  = (MODE == 0) ? ISZ : DIM;     // fp32 B n-stride
  constexpr int LDC  = (MODE == 0) ? ISZ : ((MODE == 2) ? ISH : DIM);
  constexpr int SAIT = (MODE >= 2) ? (TPL+7)/8 : 2;

  __shared__ uint4 lds[3][TPL*64];

  const int tid  = threadIdx.x;
  const int lane = tid & 63, wid = tid >> 6;

  const int bid = blockIdx.x;
  int e = 0, mb = 0, nb;
  if constexpr (MODE < 2){
    // XCD-aware: bid%8 -> experts 4x..4x+3 on one XCD (A-tile L2 reuse); 16 nblks
    const int x = bid & 7, s = bid >> 3;
    e  = x*4 + (s & 3);
    nb = (s >> 2) * (MODE == 0 ? 64 : 128);
  } else {
    mb = (bid & 15)*256; nb = (bid >> 4)*128;       // same-n adjacent (B L2-hot)
  }

  // ---- gload plane pointers (A always; B too for MODE>=2) ----
  const unsigned short* gptr[SAIT];
  #pragma unroll
  for (int i = 0; i < SAIT; ++i){
    int p = wid + i*8;
    int pp = (p < ((MODE >= 2) ? TPL : APL)) ? p : 0;
    if (pp < APL){
      int r = pp*16 + (lane & 15);
      int row;
      if constexpr (MODE == 0)      row = stok[e*CAP + r];
      else if constexpr (MODE == 1) row = e*CAP + r;
      else                          row = mb + r;
      gptr[i] = Ab + (size_t)row*KK + (lane >> 4)*8;
    } else {
      int q = pp - APL;
      const unsigned short* src = (const unsigned short*)B0v;
      int n;
      if constexpr (MODE == 2){ if (q & 1) src = (const unsigned short*)B1v;
                                n = nb + (q >> 1)*16 + (lane & 15); }
      else                    { n = nb + q*16 + (lane & 15); }
      gptr[i] = src + (size_t)n*KK + (lane >> 4)*8;
    }
  }
  auto stageG = [&](int k0, int buf){
    char* base = (char*)&lds[buf][0];
    #pragma unroll
    for (int i = 0; i < SAIT; ++i){
      int p = wid + i*8;
      if (p < ((MODE >= 2) ? TPL : APL))
        GLOAD16(gptr[i] + k0, base + p*1024);
    }
  };

  // ---- fp32 B reg-staging (MODE<=1): thread = (plane, col, k-oct) ----
  const int bq   = (tid & 127) >> 4;    // plane 0..7
  const int bcl  = tid & 15;            // col within plane
  const int boct = tid >> 7;            // k-oct 0..3
  const float* bkn = nullptr;
  if constexpr (MODE == 0){
    const float* src = (const float*)((bq & 1) ? B1v : B0v);
    int n0 = nb + (bq >> 1)*16 + bcl;
    bkn = src + (size_t)e*KK*LDB + (size_t)boct*8*LDB + n0;
  } else if constexpr (MODE == 1){
    bkn = (const float*)B0v + (size_t)e*KK*LDB + (size_t)boct*8*LDB + (nb + bq*16 + bcl);
  }
  auto loadB = [&](int k0, float (&br)[8]){
    const float* p = bkn + (size_t)k0*LDB;
    #pragma unroll
    for (int j = 0; j < 8; ++j) br[j] = p[(size_t)j*LDB];
  };
  auto writeB = [&](int buf, const float (&br)[8]){
    uint4 v;
    v.x = f2bf(br[0]) | (f2bf(br[1]) << 16);
    v.y = f2bf(br[2]) | (f2bf(br[3]) << 16);
    v.z = f2bf(br[4]) | (f2bf(br[5]) << 16);
    v.w = f2bf(br[6]) | (f2bf(br[7]) << 16);
    *(uint4*)((char*)&lds[buf][0] + (APL + bq)*1024 + boct*256 + bcl*16) = v;
  };

  // counted waits: K = own loads issued per step
  auto waitK = [&]{
    if constexpr (MODE <= 1){
      if (wid < 2) asm volatile("s_waitcnt vmcnt(10)" ::: "memory");
      else         asm volatile("s_waitcnt vmcnt(9)"  ::: "memory");
      asm volatile("s_waitcnt lgkmcnt(0)" ::: "memory");
    } else if constexpr (MODE == 2){
      asm volatile("s_waitcnt vmcnt(4)" ::: "memory");
    } else {
      asm volatile("s_waitcnt vmcnt(3)" ::: "memory");
    }
  };

  // ---- compute-side assignment: 8 waves = 2m x 4n ----
  const int wmp = (wid >> 2) * FM;
  const int wq  = wid & 3;
  f32x4 acc[FM][NBF];
  #pragma unroll
  for (int i = 0; i < FM; ++i)
    #pragma unroll
    for (int j = 0; j < NBF; ++j) acc[i][j] = f32x4{0,0,0,0};

  float brA[8], brB[8];

  // ---- prologue: two stages in flight ----
  stageG(0, 0);
  if constexpr (MODE <= 1) loadB(0, brA);
  stageG(32, 1);
  if constexpr (MODE <= 1){ loadB(32, brB); writeB(0, brA); }
  waitK();
  __builtin_amdgcn_s_barrier();

  int cons = 0;
  auto step = [&](int t, float (&brW)[8], float (&brL)[8]){
    const int stg = (cons >= 1) ? cons - 1 : 2;         // (cons+2)%3
    const int nxt = (cons == 2) ? 0 : cons + 1;
    if (t + 2 < NT){
      stageG((t+2)*32, stg);
      if constexpr (MODE <= 1) loadB((t+2)*32, brL);
    }
    __builtin_amdgcn_sched_barrier(0);                  // pin issues early
    const char* L = (const char*)&lds[cons][0];
    bf16x8 af[FM], bfr[NBF];
    #pragma unroll
    for (int i = 0; i < FM; ++i)
      af[i] = *(const bf16x8*)(L + (wmp + i)*1024 + lane*16);
    #pragma unroll
    for (int j = 0; j < NBF; ++j)
      bfr[j] = *(const bf16x8*)(L + (APL + wq*NBF + j)*1024 + lane*16);
    #pragma unroll
    for (int i = 0; i < FM; ++i)
      #pragma unroll
      for (int j = 0; j < NBF; ++j)
        acc[i][j] = __builtin_amdgcn_mfma_f32_16x16x32_bf16(af[i], bfr[j], acc[i][j], 0, 0, 0);
    if constexpr (MODE <= 1){
      if (t + 1 < NT) writeB(nxt, brW);
    }
    if (t + 2 < NT){
      waitK();                                          // leave t+2 batch in flight
    } else if (t == NT - 2){
      asm volatile("s_waitcnt vmcnt(0)" ::: "memory");
      if constexpr (MODE <= 1) asm volatile("s_waitcnt lgkmcnt(0)" ::: "memory");
    }
    if (t < NT - 1) __builtin_amdgcn_s_barrier();
    cons = nxt;
  };

  for (int t2 = 0; t2 < NT/2; ++t2){
    step(2*t2,     brB, brA);
    step(2*t2 + 1, brA, brB);
  }

  // ---- epilogue ----
  const int cl = lane & 15, rg = (lane >> 4)*4;
  #pragma unroll
  for (int i = 0; i < FM; ++i){
    #pragma unroll
    for (int r = 0; r < 4; ++r){
      const int m = (wid >> 2)*(BM/2) + i*16 + rg + r;
      if constexpr (MODE == 0){
        float g = acc[i][0][r], u = acc[i][1][r];
        float h = g / (1.f + __expf(-g)) * u;
        int gcol = nb + wq*16 + cl;
        ((unsigned short*)Co)[(size_t)(e*CAP + m)*LDC + gcol] = (unsigned short)f2bf(h);
      } else if constexpr (MODE == 2){
        #pragma unroll
        for (int jj = 0; jj < 2; ++jj){
          float g = acc[i][jj*2][r], u = acc[i][jj*2+1][r];
          float h = g / (1.f + __expf(-g)) * u;
          int gcol = nb + wq*32 + jj*16 + cl;
          ((unsigned short*)Co)[(size_t)(mb + m)*LDC + gcol] = (unsigned short)f2bf(h);
        }
      } else if constexpr (MODE == 1){
        const int slot = e*CAP + m;
        float w = sw[slot];
        if (w != 0.f){
          int tok = stok[slot];
          #pragma unroll
          for (int j = 0; j < 2; ++j){
            int c = nb + wq*32 + j*16 + cl;
            atomicAdd(&((float*)Co)[(size_t)tok*DIM + c], w * acc[i][j][r]);
          }
        }
      } else {
        #pragma unroll
        for (int j = 0; j < 2; ++j){
          int c = nb + wq*32 + j*16 + cl;
          ((float*)Co)[(size_t)(mb + m)*DIM + c] = acc[i][j][r];
        }
      }
    }
  }
}

extern "C" void kernel_launch(void* const* d_in, const int* in_sizes, int n_in,
                              void* d_out, int out_size, void* d_ws, size_t ws_size,
                              hipStream_t stream){
  const float* x  = (const float*)d_in[0];
  const float* rw = (const float*)d_in[1];
  const float* eb = (const float*)d_in[2];
  const float* wg = (const float*)d_in[3];
  const float* wu = (const float*)d_in[4];
  const float* wd = (const float*)d_in[5];
  const float* sg = (const float*)d_in[6];
  const float* su = (const float*)d_in[7];
  const float* sd = (const float*)d_in[8];
  float* out = (float*)d_out;

  char* ws = (char*)d_ws;
  unsigned short* xbf = (unsigned short*)ws; ws += (size_t)T_TOK*DIM*2;
  unsigned short* hsh = (unsigned short*)ws; ws += (size_t)T_TOK*ISH*2;
  unsigned short* hex = (unsigned short*)ws; ws += (size_t)ECAP*ISZ*2;
  unsigned short* sgb = (unsigned short*)ws; ws += (size_t)ISH*DIM*2;
  unsigned short* sub = (unsigned short*)ws; ws += (size_t)ISH*DIM*2;
  unsigned short* sdb = (unsigned short*)ws; ws += (size_t)DIM*ISH*2;
  int*   tki  = (int*)ws;   ws += (size_t)T_TOK*TOPK*4;
  float* tkw  = (float*)ws; ws += (size_t)T_TOK*TOPK*4;
  int*   stok = (int*)ws;   ws += (size_t)ECAP*4;
  float* sw   = (float*)ws; ws += (size_t)ECAP*4;

  // router (emits xbf + converts all shared weights); dispatch (self-zeroing)
  router_k<<<T_TOK/4, 256, 0, stream>>>(x, rw, eb, tki, tkw, xbf,
                                        sg, su, sd, sgb, sub, sdb);
  dispatch_k<<<2, 1024, 0, stream>>>(tki, tkw, stok, sw);

  // shared MLP: gate+up+silu -> hsh ; down -> out (plain store initializes d_out)
  gemm9_k<2><<<256, 512, 0, stream>>>(xbf, sgb, sub, hsh, nullptr, nullptr);
  gemm9_k<3><<<256, 512, 0, stream>>>(hsh, sdb, nullptr, out, nullptr, nullptr);

  // routed experts (B = fp32 weights read once, reg-transposed), 2 blocks/CU
  gemm9_k<0><<<512, 512, 0, stream>>>(xbf, wg, wu, hex, stok, sw);
  gemm9_k<1><<<512, 512, 0, stream>>>(hex, wd, nullptr, out, stok, sw);
}

// Round 13
// 497.970 us; speedup vs baseline: 1.1540x; 1.0435x over previous
//
#include <hip/hip_runtime.h>
#include <math.h>

// ---------- config ----------
#define T_TOK 4096
#define DIM   2048
#define NEXP  32
#define TOPK  4
#define CAP   160          // ceil(1.25*4096/32)
#define ECAP  (NEXP*CAP)   // 5120
#define ISZ   1024         // moe intermediate
#define ISH   2048         // shared intermediate (I*NSH)

typedef short bf16x8 __attribute__((ext_vector_type(8)));
typedef float f32x4  __attribute__((ext_vector_type(4)));

__device__ __forceinline__ unsigned int f2bf(float f){
  union { float f; unsigned int u; } v; v.f = f;
  return (v.u + 0x7fffu + ((v.u >> 16) & 1u)) >> 16;   // RNE
}

// async global->LDS, 16B/lane; LDS base wave-uniform (HW adds lane*16), global addr per-lane
#define GLOAD16(g, l) __builtin_amdgcn_global_load_lds( \
    (const __attribute__((address_space(1))) unsigned int*)(g), \
    (__attribute__((address_space(3))) unsigned int*)(l), 16, 0, 0)

// ---------- router: fp64 logits, WAVE-PARALLEL exact top-k; emits xbf; converts shared weights ----------
__global__ __launch_bounds__(256) void router_k(const float* __restrict__ x,
                                                const float* __restrict__ rw,
                                                const float* __restrict__ eb,
                                                int* __restrict__ tki,
                                                float* __restrict__ tkw,
                                                unsigned short* __restrict__ xbf,
                                                const float* __restrict__ sg,
                                                const float* __restrict__ su,
                                                const float* __restrict__ sd,
                                                unsigned short* __restrict__ sgb,
                                                unsigned short* __restrict__ sub_,
                                                unsigned short* __restrict__ sdb){
  __shared__ float  xs[4][DIM];
  __shared__ double ssh[4][NEXP];
  const int tb = blockIdx.x * 4;
  const int tid = threadIdx.x;
  for (int i = tid; i < 4*(DIM/4); i += 256){
    int t = i >> 9, c = (i & 511) << 2;
    float4 f = *(const float4*)&x[(size_t)(tb + t)*DIM + c];
    *(float4*)&xs[t][c] = f;
    uint2 w;
    w.x = f2bf(f.x) | (f2bf(f.y) << 16);
    w.y = f2bf(f.z) | (f2bf(f.w) << 16);
    *(uint2*)&xbf[(size_t)(tb + t)*DIM + c] = w;     // fused x -> bf16
  }
  __syncthreads();
  const int lane = tid & 63, wv = tid >> 6;
  for (int ei = 0; ei < 8; ++ei){
    int e = wv*8 + ei;
    double a0=0, a1=0, a2=0, a3=0;
    for (int d = lane; d < DIM; d += 64){
      double w = (double)rw[(size_t)e*DIM + d];
      a0 += (double)xs[0][d] * w;
      a1 += (double)xs[1][d] * w;
      a2 += (double)xs[2][d] * w;
      a3 += (double)xs[3][d] * w;
    }
    for (int off = 32; off; off >>= 1){
      a0 += __shfl_down(a0, off);
      a1 += __shfl_down(a1, off);
      a2 += __shfl_down(a2, off);
      a3 += __shfl_down(a3, off);
    }
    if (lane == 0){ ssh[0][e]=a0; ssh[1][e]=a1; ssh[2][e]=a2; ssh[3][e]=a3; }
  }
  __syncthreads();

  // ---- wave-parallel top-k: wave wv = token wv; lane e = expert e (lanes 32-63 mirror) ----
  {
    const int t = wv;
    const int e = lane & 31;
    double s  = 1.0 / (1.0 + exp(-ssh[t][e]));       // parallel fp64 exp across lanes
    double sc = s + (double)eb[e];
    // group top-2 sum (group g = e>>2)
    const int gb = e & ~3;
    double b0 = __shfl(sc, gb+0), b1 = __shfl(sc, gb+1);
    double b2 = __shfl(sc, gb+2), b3 = __shfl(sc, gb+3);
    double h1 = fmax(b0,b1), l1 = fmin(b0,b1);
    double h2 = fmax(b2,b3), l2 = fmin(b2,b3);
    double top = fmax(h1,h2);
    double sec = fmax(fmin(h1,h2), (h1 >= h2) ? l1 : l2);
    double gsc = top + sec;
    // rank of my group among 8 (strict >, lower index wins ties -> lax.top_k semantics)
    const int g = e >> 2;
    int grank = 0;
    #pragma unroll
    for (int h = 0; h < 8; ++h){
      double gh = __shfl(gsc, h*4);
      grank += (gh > gsc) || (gh == gsc && h < g);
    }
    double v = (grank < 3) ? sc : 0.0;               // masked score (matches jnp.where ..., 0.0)
    // top-4 argmax reduce over lanes 0..31 (xor offsets <=16 stay within the half-wave)
    double wsum = 0.0;
    int    idxr[4]; double svalr[4];                 // fully unrolled -> registers
    #pragma unroll
    for (int r = 0; r < 4; ++r){
      double bv = v; int bi = e;
      #pragma unroll
      for (int off = 16; off; off >>= 1){
        double ov = __shfl_xor(bv, off);
        int    oi = __shfl_xor(bi, off);
        if (ov > bv || (ov == bv && oi < bi)){ bv = ov; bi = oi; }
      }
      double sv = __shfl(s, bi);                     // raw sigmoid of winner
      idxr[r] = bi; svalr[r] = sv; wsum += sv;
      if (e == bi) v = -1.0e300;                     // remove winner
    }
    if (lane == 0){
      const int gt = tb + t;
      #pragma unroll
      for (int r = 0; r < 4; ++r){
        tki[gt*4 + r] = idxr[r];
        tkw[gt*4 + r] = (float)(svalr[r] / (wsum + 1e-20) * 2.5);
      }
    }
  }

  // ---- fused shared-weight fp32->bf16 (overlaps across blocks; 1024 x 1536 chunks exact cover) ----
  #pragma unroll
  for (int i = 0; i < 6; ++i){
    int g = blockIdx.x*1536 + i*256 + tid;
    int local = g & 524287;
    int sel = g >> 19;
    const float* src = (sel == 0) ? sg : (sel == 1) ? su : sd;
    unsigned short* dst = (sel == 0) ? sgb : (sel == 1) ? sub_ : sdb;
    const float4 a = *(const float4*)&src[(size_t)local*8];
    const float4 b = *(const float4*)&src[(size_t)local*8 + 4];
    uint4 v;
    v.x = f2bf(a.x) | (f2bf(a.y) << 16);
    v.y = f2bf(a.z) | (f2bf(a.w) << 16);
    v.z = f2bf(b.x) | (f2bf(b.y) << 16);
    v.w = f2bf(b.z) | (f2bf(b.w) << 16);
    *(uint4*)&dst[(size_t)local*8] = v;
  }
}

// ---------- dispatch: wave per expert, stable-order rank scan + tail zero-fill ----------
__global__ __launch_bounds__(1024) void dispatch_k(const int* __restrict__ tki,
                                                   const float* __restrict__ tkw,
                                                   int* __restrict__ stok,
                                                   float* __restrict__ sw){
  const int e = blockIdx.x*16 + (threadIdx.x >> 6);
  const int lane = threadIdx.x & 63;
  int base = 0;
  for (int it = 0; it < (T_TOK*TOPK)/64; ++it){
    if (base >= CAP) break;
    int idx = it*64 + lane;
    int ex = tki[idx];
    bool m = (ex == e);
    unsigned long long mk = __ballot(m);
    int pos = base + __popcll(mk & ((1ull << lane) - 1ull));
    if (m && pos < CAP){
      stok[e*CAP + pos] = idx >> 2;
      sw[e*CAP + pos]   = tkw[idx];
    }
    base += __popcll(mk);
  }
  const int count = (base < CAP) ? base : CAP;
  for (int s2 = count + lane; s2 < CAP; s2 += 64){
    stok[e*CAP + s2] = 0;
    sw[e*CAP + s2]   = 0.f;
  }
}

// ---------- fat-tile 8-wave MFMA GEMM, 3-deep counted-vmcnt pipeline (R10) ----------
// MODE 0 EGU: hex(bf16)=silu(X@Wg)*(X@Wu); A gathered; B fp32 [K,1024]; BN=64+64; grid 512 (2/CU).
// MODE 1 EDN: out += scatter(sw*(hex@Wd)); B fp32 [K,2048]; BN=128; grid 512 (2/CU).
// MODE 2 SGU: hsh=silu(X@sg^T)*(X@su^T); both bf16 gload; BM=256, BN=128+128; grid 256.
// MODE 3 SDN: out(f32 plain)=hsh@sd^T; both bf16 gload; BM=256, BN=128; grid 256.
template<int MODE>
__global__ __launch_bounds__(512, 2)
void gemm9_k(const unsigned short* __restrict__ Ab,
             const void* __restrict__ B0v, const void* __restrict__ B1v,
             void* __restrict__ Co,
             const int* __restrict__ stok, const float* __restrict__ sw){
  constexpr int BM   = (MODE < 2) ? 160 : 256;
  constexpr int APL  = BM/16;                       // 10,10,16,16
  constexpr int FM   = BM/32;                       // 5,5,8,8
  constexpr int KK   = (MODE == 1) ? ISZ : DIM;
  constexpr int BPL  = (MODE == 2) ? 16 : 8;        // B planes
  constexpr int NBF  = BPL/4;                       // B frags per wave (2,2,4,2)
  constexpr int TPL  = APL + BPL;                   // 18,18,32,24
  constexpr int NT   = KK/32;
  constexpr int LDB  = (MODE == 0) ? ISZ : DIM;     // fp32 B n-stride
  constexpr int LDC  = (MODE == 0) ? ISZ : ((MODE == 2) ? ISH : DIM);
  constexpr int SAIT = (MODE >= 2) ? (TPL+7)/8 : 2;

  __shared__ uint4 lds[3][TPL*64];

  const int tid  = threadIdx.x;
  const int lane = tid & 63, wid = tid >> 6;

  const int bid = blockIdx.x;
  int e = 0, mb = 0, nb;
  if constexpr (MODE < 2){
    // XCD-aware: bid%8 -> experts 4x..4x+3 on one XCD (A-tile L2 reuse); 16 nblks
    const int x = bid & 7, s = bid >> 3;
    e  = x*4 + (s & 3);
    nb = (s >> 2) * (MODE == 0 ? 64 : 128);
  } else {
    mb = (bid & 15)*256; nb = (bid >> 4)*128;       // same-n adjacent (B L2-hot)
  }

  // ---- gload plane pointers (A always; B too for MODE>=2) ----
  const unsigned short* gptr[SAIT];
  #pragma unroll
  for (int i = 0; i < SAIT; ++i){
    int p = wid + i*8;
    int pp = (p < ((MODE >= 2) ? TPL : APL)) ? p : 0;
    if (pp < APL){
      int r = pp*16 + (lane & 15);
      int row;
      if constexpr (MODE == 0)      row = stok[e*CAP + r];
      else if constexpr (MODE == 1) row = e*CAP + r;
      else                          row = mb + r;
      gptr[i] = Ab + (size_t)row*KK + (lane >> 4)*8;
    } else {
      int q = pp - APL;
      const unsigned short* src = (const unsigned short*)B0v;
      int n;
      if constexpr (MODE == 2){ if (q & 1) src = (const unsigned short*)B1v;
                                n = nb + (q >> 1)*16 + (lane & 15); }
      else                    { n = nb + q*16 + (lane & 15); }
      gptr[i] = src + (size_t)n*KK + (lane >> 4)*8;
    }
  }
  auto stageG = [&](int k0, int buf){
    char* base = (char*)&lds[buf][0];
    #pragma unroll
    for (int i = 0; i < SAIT; ++i){
      int p = wid + i*8;
      if (p < ((MODE >= 2) ? TPL : APL))
        GLOAD16(gptr[i] + k0, base + p*1024);
    }
  };

  // ---- fp32 B reg-staging (MODE<=1): thread = (plane, col, k-oct) ----
  const int bq   = (tid & 127) >> 4;    // plane 0..7
  const int bcl  = tid & 15;            // col within plane
  const int boct = tid >> 7;            // k-oct 0..3
  const float* bkn = nullptr;
  if constexpr (MODE == 0){
    const float* src = (const float*)((bq & 1) ? B1v : B0v);
    int n0 = nb + (bq >> 1)*16 + bcl;
    bkn = src + (size_t)e*KK*LDB + (size_t)boct*8*LDB + n0;
  } else if constexpr (MODE == 1){
    bkn = (const float*)B0v + (size_t)e*KK*LDB + (size_t)boct*8*LDB + (nb + bq*16 + bcl);
  }
  auto loadB = [&](int k0, float (&br)[8]){
    const float* p = bkn + (size_t)k0*LDB;
    #pragma unroll
    for (int j = 0; j < 8; ++j) br[j] = p[(size_t)j*LDB];
  };
  auto writeB = [&](int buf, const float (&br)[8]){
    uint4 v;
    v.x = f2bf(br[0]) | (f2bf(br[1]) << 16);
    v.y = f2bf(br[2]) | (f2bf(br[3]) << 16);
    v.z = f2bf(br[4]) | (f2bf(br[5]) << 16);
    v.w = f2bf(br[6]) | (f2bf(br[7]) << 16);
    *(uint4*)((char*)&lds[buf][0] + (APL + bq)*1024 + boct*256 + bcl*16) = v;
  };

  // counted waits: K = own loads issued per step
  auto waitK = [&]{
    if constexpr (MODE <= 1){
      if (wid < 2) asm volatile("s_waitcnt vmcnt(10)" ::: "memory");
      else         asm volatile("s_waitcnt vmcnt(9)"  ::: "memory");
      asm volatile("s_waitcnt lgkmcnt(0)" ::: "memory");
    } else if constexpr (MODE == 2){
      asm volatile("s_waitcnt vmcnt(4)" ::: "memory");
    } else {
      asm volatile("s_waitcnt vmcnt(3)" ::: "memory");
    }
  };

  // ---- compute-side assignment: 8 waves = 2m x 4n ----
  const int wmp = (wid >> 2) * FM;
  const int wq  = wid & 3;
  f32x4 acc[FM][NBF];
  #pragma unroll
  for (int i = 0; i < FM; ++i)
    #pragma unroll
    for (int j = 0; j < NBF; ++j) acc[i][j] = f32x4{0,0,0,0};

  float brA[8], brB[8];

  // ---- prologue: two stages in flight ----
  stageG(0, 0);
  if constexpr (MODE <= 1) loadB(0, brA);
  stageG(32, 1);
  if constexpr (MODE <= 1){ loadB(32, brB); writeB(0, brA); }
  waitK();
  __builtin_amdgcn_s_barrier();

  int cons = 0;
  auto step = [&](int t, float (&brW)[8], float (&brL)[8]){
    const int stg = (cons >= 1) ? cons - 1 : 2;         // (cons+2)%3
    const int nxt = (cons == 2) ? 0 : cons + 1;
    if (t + 2 < NT){
      stageG((t+2)*32, stg);
      if constexpr (MODE <= 1) loadB((t+2)*32, brL);
    }
    __builtin_amdgcn_sched_barrier(0);                  // pin issues early
    const char* L = (const char*)&lds[cons][0];
    bf16x8 af[FM], bfr[NBF];
    #pragma unroll
    for (int i = 0; i < FM; ++i)
      af[i] = *(const bf16x8*)(L + (wmp + i)*1024 + lane*16);
    #pragma unroll
    for (int j = 0; j < NBF; ++j)
      bfr[j] = *(const bf16x8*)(L + (APL + wq*NBF + j)*1024 + lane*16);
    #pragma unroll
    for (int i = 0; i < FM; ++i)
      #pragma unroll
      for (int j = 0; j < NBF; ++j)
        acc[i][j] = __builtin_amdgcn_mfma_f32_16x16x32_bf16(af[i], bfr[j], acc[i][j], 0, 0, 0);
    if constexpr (MODE <= 1){
      if (t + 1 < NT) writeB(nxt, brW);
    }
    if (t + 2 < NT){
      waitK();                                          // leave t+2 batch in flight
    } else if (t == NT - 2){
      asm volatile("s_waitcnt vmcnt(0)" ::: "memory");
      if constexpr (MODE <= 1) asm volatile("s_waitcnt lgkmcnt(0)" ::: "memory");
    }
    if (t < NT - 1) __builtin_amdgcn_s_barrier();
    cons = nxt;
  };

  for (int t2 = 0; t2 < NT/2; ++t2){
    step(2*t2,     brB, brA);
    step(2*t2 + 1, brA, brB);
  }

  // ---- epilogue ----
  const int cl = lane & 15, rg = (lane >> 4)*4;
  #pragma unroll
  for (int i = 0; i < FM; ++i){
    #pragma unroll
    for (int r = 0; r < 4; ++r){
      const int m = (wid >> 2)*(BM/2) + i*16 + rg + r;
      if constexpr (MODE == 0){
        float g = acc[i][0][r], u = acc[i][1][r];
        float h = g / (1.f + __expf(-g)) * u;
        int gcol = nb + wq*16 + cl;
        ((unsigned short*)Co)[(size_t)(e*CAP + m)*LDC + gcol] = (unsigned short)f2bf(h);
      } else if constexpr (MODE == 2){
        #pragma unroll
        for (int jj = 0; jj < 2; ++jj){
          float g = acc[i][jj*2][r], u = acc[i][jj*2+1][r];
          float h = g / (1.f + __expf(-g)) * u;
          int gcol = nb + wq*32 + jj*16 + cl;
          ((unsigned short*)Co)[(size_t)(mb + m)*LDC + gcol] = (unsigned short)f2bf(h);
        }
      } else if constexpr (MODE == 1){
        const int slot = e*CAP + m;
        float w = sw[slot];
        if (w != 0.f){
          int tok = stok[slot];
          #pragma unroll
          for (int j = 0; j < 2; ++j){
            int c = nb + wq*32 + j*16 + cl;
            atomicAdd(&((float*)Co)[(size_t)tok*DIM + c], w * acc[i][j][r]);
          }
        }
      } else {
        #pragma unroll
        for (int j = 0; j < 2; ++j){
          int c = nb + wq*32 + j*16 + cl;
          ((float*)Co)[(size_t)(mb + m)*DIM + c] = acc[i][j][r];
        }
      }
    }
  }
}

extern "C" void kernel_launch(void* const* d_in, const int* in_sizes, int n_in,
                              void* d_out, int out_size, void* d_ws, size_t ws_size,
                              hipStream_t stream){
  const float* x  = (const float*)d_in[0];
  const float* rw = (const float*)d_in[1];
  const float* eb = (const float*)d_in[2];
  const float* wg = (const float*)d_in[3];
  const float* wu = (const float*)d_in[4];
  const float* wd = (const float*)d_in[5];
  const float* sg = (const float*)d_in[6];
  const float* su = (const float*)d_in[7];
  const float* sd = (const float*)d_in[8];
  float* out = (float*)d_out;

  char* ws = (char*)d_ws;
  unsigned short* xbf = (unsigned short*)ws; ws += (size_t)T_TOK*DIM*2;
  unsigned short* hsh = (unsigned short*)ws; ws += (size_t)T_TOK*ISH*2;
  unsigned short* hex = (unsigned short*)ws; ws += (size_t)ECAP*ISZ*2;
  unsigned short* sgb = (unsigned short*)ws; ws += (size_t)ISH*DIM*2;
  unsigned short* sub = (unsigned short*)ws; ws += (size_t)ISH*DIM*2;
  unsigned short* sdb = (unsigned short*)ws; ws += (size_t)DIM*ISH*2;
  int*   tki  = (int*)ws;   ws += (size_t)T_TOK*TOPK*4;
  float* tkw  = (float*)ws; ws += (size_t)T_TOK*TOPK*4;
  int*   stok = (int*)ws;   ws += (size_t)ECAP*4;
  float* sw   = (float*)ws; ws += (size_t)ECAP*4;

  // router (emits xbf + converts all shared weights, wave-parallel top-k); dispatch
  router_k<<<T_TOK/4, 256, 0, stream>>>(x, rw, eb, tki, tkw, xbf,
                                        sg, su, sd, sgb, sub, sdb);
  dispatch_k<<<2, 1024, 0, stream>>>(tki, tkw, stok, sw);

  // shared MLP: gate+up+silu -> hsh ; down -> out (plain store initializes d_out)
  gemm9_k<2><<<256, 512, 0, stream>>>(xbf, sgb, sub, hsh, nullptr, nullptr);
  gemm9_k<3><<<256, 512, 0, stream>>>(hsh, sdb, nullptr, out, nullptr, nullptr);

  // routed experts (B = fp32 weights read once, reg-transposed), 2 blocks/CU
  gemm9_k<0><<<512, 512, 0, stream>>>(xbf, wg, wu, hex, stok, sw);
  gemm9_k<1><<<512, 512, 0, stream>>>(hex, wd, nullptr, out, stok, sw);
}